// Round 2
// baseline (2212.466 us; speedup 1.0000x reference)
//
#include <hip/hip_runtime.h>

#define N_NODES 10000
#define N_EDGES 640000
#define DD 128

typedef __attribute__((ext_vector_type(8))) short short8;
typedef __attribute__((ext_vector_type(8))) float f32x8;
typedef __attribute__((ext_vector_type(4))) float f32x4;

__device__ __forceinline__ float bf2f(unsigned short s) {
  union { unsigned u; float f; } v; v.u = ((unsigned)s) << 16; return v.f;
}
// pack two fp32 -> (bf16(hi)<<16)|bf16(lo), truncating: one v_perm_b32
__device__ __forceinline__ unsigned pack_bf2(float lo, float hi) {
  return __builtin_amdgcn_perm(__float_as_uint(hi), __float_as_uint(lo), 0x07060302u);
}

// Stage W (128x128 fp32 row-major) into LDS as bf16 with per-row XOR swizzle
// on 16B chunks: chunk c (cols c*8..c*8+7) of row j at slot (j*16)|(c^(j&7)).
__device__ __forceinline__ void stage_w(const float* __restrict__ W,
                                        short8* lwr) {
  const int tid = threadIdx.x;
#pragma unroll
  for (int t = 0; t < 8; ++t) {
    int s = t * 256 + tid;                    // chunk id 0..2047
    f32x8 v = *(const f32x8*)(W + (size_t)s * 8);   // coalesced 32B
    short8 av;
    unsigned* au = (unsigned*)&av;
    au[0] = pack_bf2(v[0], v[1]);
    au[1] = pack_bf2(v[2], v[3]);
    au[2] = pack_bf2(v[4], v[5]);
    au[3] = pack_bf2(v[6], v[7]);
    int j = s >> 4;
    int c = s & 15;
    lwr[(j << 4) | (c ^ (j & 7))] = av;
  }
  __syncthreads();
}

// ---------------------------------------------------------------------------
// Fused: Yp = Y @ W^T (fp32 out, bf16 MFMA) AND segY[src[e]] += Y[e] (fp32
// atomics, from the same loaded registers -> Y read exactly once).
// Per wave: 32 edges x 128 outs; block = 4 waves, 2 chunks/block.
// ---------------------------------------------------------------------------
__global__ __launch_bounds__(256, 2) void k_fused_big(
    const float* __restrict__ Y,
    const float* __restrict__ W,
    const int* __restrict__ EI,
    float* __restrict__ Yp,
    float* __restrict__ segY) {
  __shared__ short8 lwr[2048];  // 32 KB swizzled bf16 W
  stage_w(W, lwr);
  const int wid  = threadIdx.x >> 6;
  const int lane = threadIdx.x & 63;
  const int l15  = lane & 15;
  const int lg   = lane >> 4;
  const int koff = lg * 8;                     // 0,8,16,24

#pragma unroll 1
  for (int ch = 0; ch < 2; ++ch) {
    const int ebase = (blockIdx.x * 2 + ch) * 128 + wid * 32;

    // A fragments: lane holds Y[row][kk*32+koff .. +7], row = ebase+mt*16+l15
    short8 a[2][4];
#pragma unroll
    for (int mt = 0; mt < 2; ++mt) {
      const int row = ebase + mt * 16 + l15;
      const int s = EI[2 * row];               // src node
      const float* yr = Y + (size_t)row * DD;
      float* dst = segY + (size_t)s * DD;
#pragma unroll
      for (int kk = 0; kk < 4; ++kk) {
        f32x8 v = *(const f32x8*)(yr + kk * 32 + koff);
        // scatter: exact fp32 accumulation
#pragma unroll
        for (int i = 0; i < 8; ++i)
          unsafeAtomicAdd(dst + kk * 32 + koff + i, v[i]);
        // pack to bf16 for MFMA
        short8 av;
        unsigned* au = (unsigned*)&av;
        au[0] = pack_bf2(v[0], v[1]);
        au[1] = pack_bf2(v[2], v[3]);
        au[2] = pack_bf2(v[4], v[5]);
        au[3] = pack_bf2(v[6], v[7]);
        a[mt][kk] = av;
      }
    }

    f32x4 acc[2][8];
#pragma unroll
    for (int mt = 0; mt < 2; ++mt)
#pragma unroll
      for (int nt = 0; nt < 8; ++nt)
        acc[mt][nt] = (f32x4){0.f, 0.f, 0.f, 0.f};

#pragma unroll
    for (int nt = 0; nt < 8; ++nt) {
      const int j = nt * 16 + l15;             // W row = output col
#pragma unroll
      for (int kk = 0; kk < 4; ++kk) {
        const int kc = kk * 4 + lg;            // 16B chunk in row j
        short8 b = lwr[(j << 4) | (kc ^ (j & 7))];
        acc[0][nt] = __builtin_amdgcn_mfma_f32_16x16x32_bf16(a[0][kk], b, acc[0][nt], 0, 0, 0);
        acc[1][nt] = __builtin_amdgcn_mfma_f32_16x16x32_bf16(a[1][kk], b, acc[1][nt], 0, 0, 0);
      }
    }

    // C layout: col = lane&15, row = (lane>>4)*4 + reg
    const int r0 = lg * 4;
#pragma unroll
    for (int mt = 0; mt < 2; ++mt) {
#pragma unroll
      for (int reg = 0; reg < 4; ++reg) {
        float* orow = Yp + (size_t)(ebase + mt * 16 + r0 + reg) * DD + l15;
#pragma unroll
        for (int nt = 0; nt < 8; ++nt)
          orow[nt * 16] = acc[mt][nt][reg];
      }
    }
  }
}

// ---------------------------------------------------------------------------
// Small GEMM + epilogue: X' = relu(X + segY @ W^T)   (10000x128, fp32 I/O)
// ---------------------------------------------------------------------------
__global__ __launch_bounds__(256, 2) void k_gemm_small(
    const float* __restrict__ segY,
    const float* __restrict__ W,
    const float* __restrict__ X,
    float* __restrict__ Xp) {
  __shared__ short8 lwr[2048];
  stage_w(W, lwr);
  const int wid  = threadIdx.x >> 6;
  const int lane = threadIdx.x & 63;
  const int l15  = lane & 15;
  const int lg   = lane >> 4;
  const int koff = lg * 8;
  const int ebase = blockIdx.x * 128 + wid * 32;

  short8 a[2][4];
#pragma unroll
  for (int mt = 0; mt < 2; ++mt) {
    int row = ebase + mt * 16 + l15;
    if (row > N_NODES - 1) row = N_NODES - 1;  // clamp (stores guarded)
    const float* sr = segY + (size_t)row * DD + koff;
#pragma unroll
    for (int kk = 0; kk < 4; ++kk) {
      f32x8 v = *(const f32x8*)(sr + kk * 32);
      short8 av;
      unsigned* au = (unsigned*)&av;
      au[0] = pack_bf2(v[0], v[1]);
      au[1] = pack_bf2(v[2], v[3]);
      au[2] = pack_bf2(v[4], v[5]);
      au[3] = pack_bf2(v[6], v[7]);
      a[mt][kk] = av;
    }
  }

  f32x4 acc[2][8];
#pragma unroll
  for (int mt = 0; mt < 2; ++mt)
#pragma unroll
    for (int nt = 0; nt < 8; ++nt)
      acc[mt][nt] = (f32x4){0.f, 0.f, 0.f, 0.f};

#pragma unroll
  for (int nt = 0; nt < 8; ++nt) {
    const int j = nt * 16 + l15;
#pragma unroll
    for (int kk = 0; kk < 4; ++kk) {
      const int kc = kk * 4 + lg;
      short8 b = lwr[(j << 4) | (kc ^ (j & 7))];
      acc[0][nt] = __builtin_amdgcn_mfma_f32_16x16x32_bf16(a[0][kk], b, acc[0][nt], 0, 0, 0);
      acc[1][nt] = __builtin_amdgcn_mfma_f32_16x16x32_bf16(a[1][kk], b, acc[1][nt], 0, 0, 0);
    }
  }

  const int r0 = lg * 4;
#pragma unroll
  for (int mt = 0; mt < 2; ++mt) {
#pragma unroll
    for (int reg = 0; reg < 4; ++reg) {
      const int row = ebase + mt * 16 + r0 + reg;
      if (row < N_NODES) {
#pragma unroll
        for (int nt = 0; nt < 8; ++nt) {
          const int idx = row * DD + nt * 16 + l15;
          float o = acc[mt][nt][reg] + X[idx];
          Xp[idx] = o > 0.f ? o : 0.f;
        }
      }
    }
  }
}

extern "C" void kernel_launch(void* const* d_in, const int* in_sizes, int n_in,
                              void* d_out, int out_size, void* d_ws, size_t ws_size,
                              hipStream_t stream) {
  const float* X  = (const float*)d_in[0];
  const float* Y  = (const float*)d_in[1];
  const float* W  = (const float*)d_in[2];
  const int*   EI = (const int*)d_in[3];

  float* Xp = (float*)d_out;
  float* Yp = Xp + (size_t)N_NODES * DD;   // outputs concatenated: X' then Y'
  float* segY = (float*)d_ws;              // 10000*128 fp32 = 5.12 MB

  hipMemsetAsync(segY, 0, (size_t)N_NODES * DD * sizeof(float), stream);
  k_fused_big<<<2500, 256, 0, stream>>>(Y, W, EI, Yp, segY);
  k_gemm_small<<<(N_NODES + 127) / 128, 256, 0, stream>>>(segY, W, X, Xp);
}

// Round 3
// 315.995 us; speedup vs baseline: 7.0016x; 7.0016x over previous
//
#include <hip/hip_runtime.h>

#define N_NODES 10000
#define N_EDGES 640000
#define DD 128

typedef __attribute__((ext_vector_type(8))) short short8;
typedef __attribute__((ext_vector_type(8))) float f32x8;
typedef __attribute__((ext_vector_type(4))) float f32x4;
typedef __attribute__((ext_vector_type(2))) float f32x2;

// pack two fp32 -> (bf16(hi)<<16)|bf16(lo), truncating: one v_perm_b32
__device__ __forceinline__ unsigned pack_bf2(float lo, float hi) {
  return __builtin_amdgcn_perm(__float_as_uint(hi), __float_as_uint(lo), 0x07060302u);
}

// Stage W (128x128 fp32 row-major) into LDS as bf16 with per-row XOR swizzle
// on 16B chunks: chunk c (cols c*8..c*8+7) of row j at slot (j*16)|(c^(j&7)).
__device__ __forceinline__ void stage_w(const float* __restrict__ W,
                                        short8* lwr) {
  const int tid = threadIdx.x;
#pragma unroll
  for (int t = 0; t < 8; ++t) {
    int s = t * 256 + tid;                          // chunk id 0..2047
    f32x8 v = *(const f32x8*)(W + (size_t)s * 8);   // coalesced 32B
    short8 av;
    unsigned* au = (unsigned*)&av;
    au[0] = pack_bf2(v[0], v[1]);
    au[1] = pack_bf2(v[2], v[3]);
    au[2] = pack_bf2(v[4], v[5]);
    au[3] = pack_bf2(v[6], v[7]);
    int j = s >> 4;
    int c = s & 15;
    lwr[(j << 4) | (c ^ (j & 7))] = av;
  }
  __syncthreads();
}

// ---------------------------------------------------------------------------
// CSR build: histogram -> scan -> fill
// ---------------------------------------------------------------------------
__global__ __launch_bounds__(256) void k_hist(const int* __restrict__ EI,
                                              int* __restrict__ count) {
  const int e = blockIdx.x * 256 + threadIdx.x;
  atomicAdd(&count[EI[2 * e]], 1);
}

__global__ __launch_bounds__(1024) void k_scan(const int* __restrict__ count,
                                               int* __restrict__ rowptr,
                                               int* __restrict__ cursor) {
  __shared__ int part[1024];
  const int tid = threadIdx.x;
  const int base = tid * 10;
  int local[10];
  int s = 0;
#pragma unroll
  for (int i = 0; i < 10; ++i) {
    const int idx = base + i;
    const int v = (idx < N_NODES) ? count[idx] : 0;
    local[i] = s;
    s += v;
  }
  part[tid] = s;
  __syncthreads();
  for (int off = 1; off < 1024; off <<= 1) {
    int v = 0;
    if (tid >= off) v = part[tid - off];
    __syncthreads();
    if (tid >= off) part[tid] += v;
    __syncthreads();
  }
  const int excl = (tid > 0) ? part[tid - 1] : 0;
#pragma unroll
  for (int i = 0; i < 10; ++i) {
    const int idx = base + i;
    if (idx < N_NODES) {
      const int r = excl + local[i];
      rowptr[idx] = r;
      cursor[idx] = r;
    }
  }
  if (tid == 1023) rowptr[N_NODES] = part[1023];
}

__global__ __launch_bounds__(256) void k_fill(const int* __restrict__ EI,
                                              int* __restrict__ cursor,
                                              int* __restrict__ col) {
  const int e = blockIdx.x * 256 + threadIdx.x;
  const int s = EI[2 * e];
  const int pos = atomicAdd(&cursor[s], 1);
  col[pos] = e;
}

// ---------------------------------------------------------------------------
// Big GEMM: Yp = Y @ W^T   (640000x128 @ 128x128), fp32 I/O, bf16 MFMA
// Per wave: 32 edges x 128 outs; block = 4 waves, 2 chunks/block.
// ---------------------------------------------------------------------------
__global__ __launch_bounds__(256, 2) void k_gemm_big(
    const float* __restrict__ Y,
    const float* __restrict__ W,
    float* __restrict__ Yp) {
  __shared__ short8 lwr[2048];  // 32 KB swizzled bf16 W
  stage_w(W, lwr);
  const int wid  = threadIdx.x >> 6;
  const int lane = threadIdx.x & 63;
  const int l15  = lane & 15;
  const int lg   = lane >> 4;
  const int koff = lg * 8;

#pragma unroll 1
  for (int ch = 0; ch < 2; ++ch) {
    const int ebase = (blockIdx.x * 2 + ch) * 128 + wid * 32;

    short8 a[2][4];
#pragma unroll
    for (int mt = 0; mt < 2; ++mt) {
      const float* yr = Y + (size_t)(ebase + mt * 16 + l15) * DD;
#pragma unroll
      for (int kk = 0; kk < 4; ++kk) {
        f32x8 v = *(const f32x8*)(yr + kk * 32 + koff);
        short8 av;
        unsigned* au = (unsigned*)&av;
        au[0] = pack_bf2(v[0], v[1]);
        au[1] = pack_bf2(v[2], v[3]);
        au[2] = pack_bf2(v[4], v[5]);
        au[3] = pack_bf2(v[6], v[7]);
        a[mt][kk] = av;
      }
    }

    f32x4 acc[2][8];
#pragma unroll
    for (int mt = 0; mt < 2; ++mt)
#pragma unroll
      for (int nt = 0; nt < 8; ++nt)
        acc[mt][nt] = (f32x4){0.f, 0.f, 0.f, 0.f};

#pragma unroll
    for (int nt = 0; nt < 8; ++nt) {
      const int j = nt * 16 + l15;
#pragma unroll
      for (int kk = 0; kk < 4; ++kk) {
        const int kc = kk * 4 + lg;
        short8 b = lwr[(j << 4) | (kc ^ (j & 7))];
        acc[0][nt] = __builtin_amdgcn_mfma_f32_16x16x32_bf16(a[0][kk], b, acc[0][nt], 0, 0, 0);
        acc[1][nt] = __builtin_amdgcn_mfma_f32_16x16x32_bf16(a[1][kk], b, acc[1][nt], 0, 0, 0);
      }
    }

    // C layout: col = lane&15, row = (lane>>4)*4 + reg
    const int r0 = lg * 4;
#pragma unroll
    for (int mt = 0; mt < 2; ++mt) {
#pragma unroll
      for (int reg = 0; reg < 4; ++reg) {
        float* orow = Yp + (size_t)(ebase + mt * 16 + r0 + reg) * DD + l15;
#pragma unroll
        for (int nt = 0; nt < 8; ++nt)
          orow[nt * 16] = acc[mt][nt][reg];
      }
    }
  }
}

// ---------------------------------------------------------------------------
// Gather + epilogue: X'[n] = relu(X[n] + sum_{e in CSR[n]} Yp[e])
// one wave per node; lane covers cols 2*lane, 2*lane+1 (512B coalesced rows)
// ---------------------------------------------------------------------------
__global__ __launch_bounds__(256) void k_gather(
    const float* __restrict__ Yp,
    const int* __restrict__ rowptr,
    const int* __restrict__ col,
    const float* __restrict__ X,
    float* __restrict__ Xp) {
  const int node = blockIdx.x * 4 + (threadIdx.x >> 6);
  const int lane = threadIdx.x & 63;
  const size_t co = 2 * lane;
  const int b  = rowptr[node];
  const int en = rowptr[node + 1];

  f32x2 acc = *(const f32x2*)(X + (size_t)node * DD + co);
  int i = b;
  for (; i + 4 <= en; i += 4) {
    const int e0 = col[i], e1 = col[i + 1], e2 = col[i + 2], e3 = col[i + 3];
    f32x2 v0 = *(const f32x2*)(Yp + (size_t)e0 * DD + co);
    f32x2 v1 = *(const f32x2*)(Yp + (size_t)e1 * DD + co);
    f32x2 v2 = *(const f32x2*)(Yp + (size_t)e2 * DD + co);
    f32x2 v3 = *(const f32x2*)(Yp + (size_t)e3 * DD + co);
    acc += v0; acc += v1; acc += v2; acc += v3;
  }
  for (; i < en; ++i) {
    const int e0 = col[i];
    acc += *(const f32x2*)(Yp + (size_t)e0 * DD + co);
  }
  f32x2 r;
  r[0] = acc[0] > 0.f ? acc[0] : 0.f;
  r[1] = acc[1] > 0.f ? acc[1] : 0.f;
  *(f32x2*)(Xp + (size_t)node * DD + co) = r;
}

extern "C" void kernel_launch(void* const* d_in, const int* in_sizes, int n_in,
                              void* d_out, int out_size, void* d_ws, size_t ws_size,
                              hipStream_t stream) {
  const float* X  = (const float*)d_in[0];
  const float* Y  = (const float*)d_in[1];
  const float* W  = (const float*)d_in[2];
  const int*   EI = (const int*)d_in[3];

  float* Xp = (float*)d_out;
  float* Yp = Xp + (size_t)N_NODES * DD;   // outputs concatenated: X' then Y'

  int* w      = (int*)d_ws;
  int* count  = w;                // 10000
  int* rowptr = w + 10000;        // 10001
  int* cursor = w + 20001;        // 10000
  int* col    = w + 30001;        // 640000   (total ~2.68 MB of ws)

  hipMemsetAsync(count, 0, N_NODES * sizeof(int), stream);
  k_hist<<<N_EDGES / 256, 256, 0, stream>>>(EI, count);
  k_scan<<<1, 1024, 0, stream>>>(count, rowptr, cursor);
  k_fill<<<N_EDGES / 256, 256, 0, stream>>>(EI, cursor, col);
  k_gemm_big<<<2500, 256, 0, stream>>>(Y, W, Yp);
  k_gather<<<2500, 256, 0, stream>>>(Yp, rowptr, col, X, Xp);
}